// Round 2
// baseline (292.389 us; speedup 1.0000x reference)
//
#include <hip/hip_runtime.h>

// GCN encoder: conv1(128->128) + rrelu + conv2(128->64), N=100K, E=1.6M.
// R8: aggs are wave-latency-throughput bound; 2 nodes/wave, 12 gathers/wave.
// R9 FAILED: sched_barrier(0) left VGPR=48 (12 int4 dests alone need 48) ->
//     gathers still serialized; dur unchanged. Register-destination loads
//     cannot be forced into flight at HIP level.
// R10: issue gathers with global_load_lds (NO dest regs -> compiler cannot
//     consume-early/serialize; all 12 in flight by construction). Counted
//     waits: vmcnt(6) -> accumulate node A from LDS while B's 6 loads still
//     fly -> vmcnt(0) -> node B. LDS 48KB/block (C=128) -> 3 blocks/CU,
//     same occupancy as now but ~12 outstanding gathers/wave instead of ~2.

#define C_IN   128
#define C_MID  128
#define C_OUT2 64
#define SLOT_CAP 64    // 63 edges + self; Poisson(16): P(deg>63) ~ 1e-20
#define SORT_SH  9     // bucket = v >> 9 (512 nodes/bucket)
#define SORT_W   196   // ceil(100000/512)
#define SORT_CAP 16384 // cap per bucket; mean 8192, std ~90
#define P1_EPT   8     // edges per thread, phase A (2048/block, 782 blocks)

typedef __attribute__((ext_vector_type(8))) short short8;
typedef __attribute__((ext_vector_type(4))) float floatx4;
typedef __attribute__((ext_vector_type(2))) float f32x2;

__device__ __constant__ float kSlope = 0.22916666666666666f; // (1/8 + 1/3)/2

__device__ __forceinline__ unsigned short f2bf(float f) {  // fp32 -> bf16 RNE
    unsigned u = __builtin_bit_cast(unsigned, f);
    u = (u + 0x7fffu + ((u >> 16) & 1u)) >> 16;
    return (unsigned short)u;
}
__device__ __forceinline__ f32x2 bfpair(int x) {  // packed bf16 pair -> 2 fp32
    return (f32x2){__builtin_bit_cast(float, (unsigned)x << 16),
                   __builtin_bit_cast(float, (unsigned)(x & 0xffff0000))};
}

// async gather: per-lane global src, wave-uniform LDS base; HW writes
// ldsbase + lane*16. No VGPR destination -> guaranteed in flight.
__device__ __forceinline__ void gload_lds16(const void* g, void* l) {
    __builtin_amdgcn_global_load_lds(
        (const __attribute__((address_space(1))) void*)g,
        (__attribute__((address_space(3))) void*)l, 16, 0, 0);
}

// ---------------- Phase A: bucket sort by destination (+fused prep_w) ------
__global__ __launch_bounds__(256) void sort_prep_kernel(
        const int* __restrict__ ei, int2* __restrict__ sorted,
        int* __restrict__ bcur,
        const float* __restrict__ W1, const float* __restrict__ W2,
        ushort* __restrict__ W1T, ushort* __restrict__ W2T,
        int E, int p1b) {
    if (blockIdx.x >= p1b) {  // ---- prep_w: W transpose + bf16 ----
        int t = (blockIdx.x - p1b) * 256 + threadIdx.x;
        if (t < C_MID * C_IN) {
            int nn = t >> 7, k = t & 127;
            W1T[t] = f2bf(W1[k * C_MID + nn]);
        } else {
            int i = t - C_MID * C_IN;
            if (i < C_OUT2 * C_MID) {
                int nn = i >> 7, k = i & 127;
                W2T[i] = f2bf(W2[k * C_OUT2 + nn]);
            }
        }
        return;
    }
    __shared__ int hist[SORT_W], goff[SORT_W], cur[SORT_W];
    const int tid = threadIdx.x;
    for (int i = tid; i < SORT_W; i += 256) { hist[i] = 0; cur[i] = 0; }
    __syncthreads();
    const int base = blockIdx.x * (P1_EPT * 256);
#pragma unroll
    for (int k = 0; k < P1_EPT; ++k) {
        int e = base + k * 256 + tid;
        if (e < E) atomicAdd(&hist[ei[E + e] >> SORT_SH], 1);
    }
    __syncthreads();
    for (int i = tid; i < SORT_W; i += 256)
        if (hist[i]) goff[i] = atomicAdd(&bcur[i], hist[i]);
    __syncthreads();
#pragma unroll
    for (int k = 0; k < P1_EPT; ++k) {
        int e = base + k * 256 + tid;
        if (e < E) {
            int v = ei[E + e], u = ei[e];
            int b = v >> SORT_SH;
            int p = goff[b] + atomicAdd(&cur[b], 1);
            if (p < SORT_CAP) sorted[(size_t)b * SORT_CAP + p] = (int2){u, v};
        }
    }
}

// ---------------- shared gemm body: Y[n,CO](bf16) = A[n,128] @ W[128,CO] ----
// 16x16x32 layouts (m89-verified): A[m=lane&15][k=(lane>>4)*8+j],
// B[k][n=lane&15], C/D col=lane&15 row=(lane>>4)*4+i.
template <int CO, bool ABF>
__device__ __forceinline__ void gemm_body(char* smem, int row0,
        const void* __restrict__ Xv, const ushort* __restrict__ WT,
        ushort* __restrict__ Y, int n) {
    constexpr int LDW = 136;
    constexpr int NT = CO / 16;
    ushort* Ws = (ushort*)smem;
    const int tid = threadIdx.x, wave = tid >> 6, lane = tid & 63;
    const int m = lane & 15, q = lane >> 4;

#pragma unroll
    for (int c = 0; c < CO / 16; ++c) {
        int id = tid + c * 256;
        int r = id >> 4, h8 = id & 15;
        *(int4*)&Ws[r * LDW + h8 * 8] = ((const int4*)(WT + r * C_IN))[h8];
    }
    __syncthreads();

    const int rowA = min(row0 + wave * 16 + m, n - 1);
    floatx4 acc[NT];
#pragma unroll
    for (int c = 0; c < NT; ++c) acc[c] = (floatx4){0.f, 0.f, 0.f, 0.f};

#pragma unroll
    for (int s = 0; s < 4; ++s) {            // k = 32*s .. 32*s+31
        short8 af;
        if constexpr (ABF) {
            af = *(const short8*)((const ushort*)Xv + (size_t)rowA * C_IN + s * 32 + q * 8);
        } else {
            const float* xp = (const float*)Xv + (size_t)rowA * C_IN + s * 32 + q * 8;
            float4 a0 = *(const float4*)xp;
            float4 a1 = *(const float4*)(xp + 4);
            union { unsigned short us[8]; short8 v; } t;
            t.us[0] = f2bf(a0.x); t.us[1] = f2bf(a0.y); t.us[2] = f2bf(a0.z); t.us[3] = f2bf(a0.w);
            t.us[4] = f2bf(a1.x); t.us[5] = f2bf(a1.y); t.us[6] = f2bf(a1.z); t.us[7] = f2bf(a1.w);
            af = t.v;
        }
#pragma unroll
        for (int c = 0; c < NT; ++c) {
            short8 bf = *(short8*)&Ws[(c * 16 + m) * LDW + s * 32 + q * 8];
            acc[c] = __builtin_amdgcn_mfma_f32_16x16x32_bf16(af, bf, acc[c], 0, 0, 0);
        }
    }
#pragma unroll
    for (int c = 0; c < NT; ++c)
#pragma unroll
        for (int i = 0; i < 4; ++i) {
            int rr = row0 + wave * 16 + q * 4 + i;
            if (rr < n) Y[(size_t)rr * CO + c * 16 + m] = f2bf(acc[c][i]);
        }
}

// ---------------- Phase B (per-bucket CSR via LDS atomics) + fused gemm1 ----
// Emits slots with the self-loop appended (slots[v][deg]=v) and cnt = deg+1.
__global__ __launch_bounds__(256) void csr_gemm1_kernel(
        const int2* __restrict__ sorted, const int* __restrict__ bcur,
        int* __restrict__ cnt, float* __restrict__ dinv,
        int* __restrict__ slots,
        const float* __restrict__ X, const ushort* __restrict__ W1T,
        ushort* __restrict__ h1, int n) {
    __shared__ __align__(16) char smem[C_MID * 136 * 2];
    if (blockIdx.x < SORT_W) {
        int* lc = (int*)smem;                  // 512 local degree counters
        const int b = blockIdx.x, tid = threadIdx.x;
        const int base_v = b << SORT_SH;
        for (int i = tid; i < 512; i += 256) lc[i] = 0;
        __syncthreads();
        const int nb = min(bcur[b], SORT_CAP);
        const int2* src = sorted + (size_t)b * SORT_CAP;
        for (int i = tid; i < nb; i += 256) {
            int2 e = src[i];
            int pos = atomicAdd(&lc[e.y - base_v], 1);   // LDS atomic
            if (pos < SLOT_CAP - 1) slots[(size_t)e.y * SLOT_CAP + pos] = e.x;
        }
        __syncthreads();
        for (int i = tid; i < 512; i += 256) {
            int v = base_v + i;
            if (v < n) {
                int deg = lc[i];
                int st = min(deg, SLOT_CAP - 1);
                slots[(size_t)v * SLOT_CAP + st] = v;    // self-loop slot
                cnt[v] = st + 1;
                dinv[v] = rsqrtf((float)(deg + 1));
            }
        }
        return;
    }
    gemm_body<C_MID, false>(smem, (blockIdx.x - SORT_W) * 64, X, W1T, h1, n);
}

// ---------------- standalone gemm2 ----------------
template <int CO, bool ABF>
__global__ __launch_bounds__(256) void gemm_mfma(const void* __restrict__ Xv,
                                                 const ushort* __restrict__ WT,
                                                 ushort* __restrict__ Y, int n) {
    __shared__ __align__(16) char smem[CO * 136 * 2];
    gemm_body<CO, ABF>(smem, blockIdx.x * 64, Xv, WT, Y, n);
}

// ---------------- aggregation: 2 nodes/wave, async LDS-staged gathers ------
// GS = C/8 lanes per row at 16B/lane; NG = 64/GS rows per load inst; NCH =
// 24/NG chunks per node. All 2*NCH gathers issue as global_load_lds (no dest
// regs -> guaranteed in flight), then vmcnt(NCH): accumulate node A from LDS
// while node B's loads fly, vmcnt(0): node B. Slot loads are unconditional
// (poison clamped to [0,n-1]; shfl indices clamped to last<lim so poisoned
// lanes never selected). Group 0 stores node A, group 1 node B.
template <int C, bool DO_RRELU, bool OUT_BF>
__global__ __launch_bounds__(256) void agg_kernel(const ushort* __restrict__ H,
                                                  const int* __restrict__ slots,
                                                  const int* __restrict__ cnt,
                                                  const float* __restrict__ dinv,
                                                  const float* __restrict__ bias,
                                                  void* __restrict__ outv, int n) {
    constexpr int GS = C / 8;        // 16 (C=128) / 8 (C=64)
    constexpr int NG = 64 / GS;      // rows per load: 4 / 8
    constexpr int NCH = 24 / NG;     // straight-line chunks per node: 6 / 3
    // per wave: 2 nodes * NCH KB; 4 waves per block
    __shared__ __align__(16) char glds[4 * 2 * NCH * 1024];
    const int wave = threadIdx.x >> 6, lane = threadIdx.x & 63;
    const int vA = blockIdx.x * 8 + wave * 2;
    if (vA >= n) return;
    const int vB = (vA + 1 < n) ? vA + 1 : vA;   // odd tail: duplicate (benign)
    char* ldsA = glds + wave * (2 * NCH * 1024);
    char* ldsB = ldsA + NCH * 1024;

    // prologue: all loads issued up front, minimal dependency chains
    int rawA = slots[(size_t)vA * SLOT_CAP + lane];
    int rawB = slots[(size_t)vB * SLOT_CAP + lane];
    const int limA = cnt[vA], limB = cnt[vB];
    const float dvA = dinv[vA], dvB = dinv[vB];
    const int uA = min(max(rawA, 0), n - 1);     // poison-safe
    const int uB = min(max(rawB, 0), n - 1);
    const float wA_l = dinv[uA] * dvA;
    const float wB_l = dinv[uB] * dvB;
    const int lastA = limA - 1, lastB = limB - 1;

    const int g = lane / GS, s = lane % GS;

    // issue all 2*NCH async gathers; no VGPR destinations
    float wwA[NCH], wwB[NCH];
#pragma unroll
    for (int t = 0; t < NCH; ++t) {
        int jj = t * NG + g;
        int cA = jj < lastA ? jj : lastA;
        int usA = __shfl(uA, cA);
        float wsA = __shfl(wA_l, cA);
        wwA[t] = (jj < limA) ? wsA : 0.f;
        gload_lds16(H + (size_t)usA * C + s * 8, ldsA + t * 1024);
    }
#pragma unroll
    for (int t = 0; t < NCH; ++t) {
        int jj = t * NG + g;
        int cB = jj < lastB ? jj : lastB;
        int usB = __shfl(uB, cB);
        float wsB = __shfl(wB_l, cB);
        wwB[t] = (jj < limB) ? wsB : 0.f;
        gload_lds16(H + (size_t)usB * C + s * 8, ldsB + t * 1024);
    }

    f32x2 accA[4], accB[4];
#pragma unroll
    for (int k = 0; k < 4; ++k) { accA[k] = (f32x2){0.f, 0.f}; accB[k] = (f32x2){0.f, 0.f}; }

    // node A ready (oldest NCH loads), B's still in flight
    if constexpr (NCH == 6) asm volatile("s_waitcnt vmcnt(6)" ::: "memory");
    else                    asm volatile("s_waitcnt vmcnt(3)" ::: "memory");
    __builtin_amdgcn_sched_barrier(0);
#pragma unroll
    for (int t = 0; t < NCH; ++t) {
        const int4 d = *(const int4*)(ldsA + t * 1024 + lane * 16);
        accA[0] += bfpair(d.x) * wwA[t]; accA[1] += bfpair(d.y) * wwA[t];
        accA[2] += bfpair(d.z) * wwA[t]; accA[3] += bfpair(d.w) * wwA[t];
    }
    asm volatile("s_waitcnt vmcnt(0)" ::: "memory");
    __builtin_amdgcn_sched_barrier(0);
#pragma unroll
    for (int t = 0; t < NCH; ++t) {
        const int4 d = *(const int4*)(ldsB + t * 1024 + lane * 16);
        accB[0] += bfpair(d.x) * wwB[t]; accB[1] += bfpair(d.y) * wwB[t];
        accB[2] += bfpair(d.z) * wwB[t]; accB[3] += bfpair(d.w) * wwB[t];
    }

    // rare tails (wave-uniform, P(lim>24) ~ 3.4% each)
    for (int j = 24; j < limA; j += NG) {
        int jj = j + g;
        int c = jj < lastA ? jj : lastA;
        int u = __shfl(uA, c);
        float wv = __shfl(wA_l, c);
        float wgt = (jj < limA) ? wv : 0.f;
        const int4 d = *(const int4*)(H + (size_t)u * C + s * 8);
        accA[0] += bfpair(d.x) * wgt; accA[1] += bfpair(d.y) * wgt;
        accA[2] += bfpair(d.z) * wgt; accA[3] += bfpair(d.w) * wgt;
    }
    for (int j = 24; j < limB; j += NG) {
        int jj = j + g;
        int c = jj < lastB ? jj : lastB;
        int u = __shfl(uB, c);
        float wv = __shfl(wB_l, c);
        float wgt = (jj < limB) ? wv : 0.f;
        const int4 d = *(const int4*)(H + (size_t)u * C + s * 8);
        accB[0] += bfpair(d.x) * wgt; accB[1] += bfpair(d.y) * wgt;
        accB[2] += bfpair(d.z) * wgt; accB[3] += bfpair(d.w) * wgt;
    }

    float a[8], b8[8];
#pragma unroll
    for (int k = 0; k < 4; ++k) {
        a[2 * k] = accA[k].x; a[2 * k + 1] = accA[k].y;
        b8[2 * k] = accB[k].x; b8[2 * k + 1] = accB[k].y;
    }
#pragma unroll
    for (int k = 0; k < 8; ++k)
#pragma unroll
        for (int off = GS; off < 64; off <<= 1) {
            a[k] += __shfl_xor(a[k], off);
            b8[k] += __shfl_xor(b8[k], off);
        }

    if (g < 2) {
        const int v = (g == 0) ? vA : vB;
        float r[8];
#pragma unroll
        for (int k = 0; k < 8; ++k) {
            float t = (g == 0) ? a[k] : b8[k];
            r[k] = t + bias[s * 8 + k];
            if (DO_RRELU) r[k] = (r[k] >= 0.f) ? r[k] : r[k] * kSlope;
        }
        if constexpr (OUT_BF) {
            union { ushort us[8]; int4 v4; } o;
#pragma unroll
            for (int k = 0; k < 8; ++k) o.us[k] = f2bf(r[k]);
            *(int4*)((ushort*)outv + (size_t)v * C + s * 8) = o.v4;
        } else {
            float* op = (float*)outv + (size_t)v * C + s * 8;
            *(float4*)op       = (float4){r[0], r[1], r[2], r[3]};
            *(float4*)(op + 4) = (float4){r[4], r[5], r[6], r[7]};
        }
    }
}

extern "C" void kernel_launch(void* const* d_in, const int* in_sizes, int n_in,
                              void* d_out, int out_size, void* d_ws, size_t ws_size,
                              hipStream_t stream) {
    const float* x  = (const float*)d_in[0];
    const int*   ei = (const int*)d_in[1];
    const float* W1 = (const float*)d_in[2];
    const float* b1 = (const float*)d_in[3];
    const float* W2 = (const float*)d_in[4];
    const float* b2 = (const float*)d_in[5];
    const int n = in_sizes[0] / C_IN;   // 100000
    const int E = in_sizes[1] / 2;      // 1600000

    char* w = (char*)d_ws;
    auto alloc = [&](size_t bytes) -> char* {
        char* p = w; w += (bytes + 255) & ~(size_t)255; return p;
    };
    int*    cnt    = (int*)alloc((size_t)n * 4);
    float*  dinv   = (float*)alloc((size_t)n * 4);
    int*    slots  = (int*)alloc((size_t)n * SLOT_CAP * 4);
    ushort* h1     = (ushort*)alloc((size_t)n * C_MID * 2);   // bf16
    ushort* h2     = (ushort*)alloc((size_t)n * C_MID * 2);   // bf16
    ushort* h3     = h1;                                      // reuse after agg1
    ushort* W1T    = (ushort*)alloc((size_t)C_MID * C_IN * 2);
    ushort* W2T    = (ushort*)alloc((size_t)C_OUT2 * C_MID * 2);
    int2*   sorted = (int2*)alloc((size_t)SORT_W * SORT_CAP * 8);
    int*    bcur   = (int*)alloc((size_t)SORT_W * 4);

    const int p1b = (E + P1_EPT * 256 - 1) / (P1_EPT * 256);   // 782
    const int prep_blocks = (C_MID * C_IN + C_OUT2 * C_MID + 255) / 256;  // 96
    const int gemm1_blocks = (n + 63) / 64;                    // 1563

    hipMemsetAsync(bcur, 0, (size_t)SORT_W * 4, stream);
    sort_prep_kernel<<<p1b + prep_blocks, 256, 0, stream>>>(
        ei, sorted, bcur, W1, W2, W1T, W2T, E, p1b);
    csr_gemm1_kernel<<<SORT_W + gemm1_blocks, 256, 0, stream>>>(
        sorted, bcur, cnt, dinv, slots, x, W1T, h1, n);
    agg_kernel<C_MID, true, true><<<(n + 7) / 8, 256, 0, stream>>>(
        h1, slots, cnt, dinv, b1, h2, n);
    gemm_mfma<C_OUT2, true><<<(n + 63) / 64, 256, 0, stream>>>(h2, W2T, h3, n);
    agg_kernel<C_OUT2, false, false><<<(n + 7) / 8, 256, 0, stream>>>(
        h3, slots, cnt, dinv, b2, d_out, n);
}

// Round 3
// 266.140 us; speedup vs baseline: 1.0986x; 1.0986x over previous
//
#include <hip/hip_runtime.h>

// GCN encoder: conv1(128->128) + rrelu + conv2(128->64), N=100K, E=1.6M.
// R8: aggs are wave-latency-throughput bound; 2 nodes/wave, 12 gathers/wave.
// R9 NULL: sched_barrier left VGPR=48, dur unchanged.
// R10 REGRESSED (78.6us): global_load_lds proved loads in flight, yet BW
//     DROPPED with occupancy (44->28.6%) -> aggs are bound by per-CU
//     scattered-line throughput x concurrency, not per-wave MLP. FETCH
//     arithmetic: 202MB ~= row-gather L2 misses (435MB reads, ~54% hit) -
//     irreducible for a random graph. Revert agg core to R9.
// R11: fuse gemm2 INTO agg1's epilogue. Each block holds its 8 output rows;
//     rows -> 2KB LDS -> each wave does 4 MFMAs (16 rows x 16 cols x K=128)
//     against W2T and stores h3 directly. Kills the gemm2 dispatch and the
//     h2 25MB write + 25.6MB read. Bitwise-identical math to h2->gemm2.

#define C_IN   128
#define C_MID  128
#define C_OUT2 64
#define SLOT_CAP 64    // 63 edges + self; Poisson(16): P(deg>63) ~ 1e-20
#define SORT_SH  9     // bucket = v >> 9 (512 nodes/bucket)
#define SORT_W   196   // ceil(100000/512)
#define SORT_CAP 16384 // cap per bucket; mean 8192, std ~90
#define P1_EPT   8     // edges per thread, phase A (2048/block, 782 blocks)

typedef __attribute__((ext_vector_type(8))) short short8;
typedef __attribute__((ext_vector_type(4))) float floatx4;
typedef __attribute__((ext_vector_type(2))) float f32x2;

__device__ __constant__ float kSlope = 0.22916666666666666f; // (1/8 + 1/3)/2

__device__ __forceinline__ unsigned short f2bf(float f) {  // fp32 -> bf16 RNE
    unsigned u = __builtin_bit_cast(unsigned, f);
    u = (u + 0x7fffu + ((u >> 16) & 1u)) >> 16;
    return (unsigned short)u;
}
__device__ __forceinline__ f32x2 bfpair(int x) {  // packed bf16 pair -> 2 fp32
    return (f32x2){__builtin_bit_cast(float, (unsigned)x << 16),
                   __builtin_bit_cast(float, (unsigned)(x & 0xffff0000))};
}

// ---------------- Phase A: bucket sort by destination (+fused prep_w) ------
__global__ __launch_bounds__(256) void sort_prep_kernel(
        const int* __restrict__ ei, int2* __restrict__ sorted,
        int* __restrict__ bcur,
        const float* __restrict__ W1, const float* __restrict__ W2,
        ushort* __restrict__ W1T, ushort* __restrict__ W2T,
        int E, int p1b) {
    if (blockIdx.x >= p1b) {  // ---- prep_w: W transpose + bf16 ----
        int t = (blockIdx.x - p1b) * 256 + threadIdx.x;
        if (t < C_MID * C_IN) {
            int nn = t >> 7, k = t & 127;
            W1T[t] = f2bf(W1[k * C_MID + nn]);
        } else {
            int i = t - C_MID * C_IN;
            if (i < C_OUT2 * C_MID) {
                int nn = i >> 7, k = i & 127;
                W2T[i] = f2bf(W2[k * C_OUT2 + nn]);
            }
        }
        return;
    }
    __shared__ int hist[SORT_W], goff[SORT_W], cur[SORT_W];
    const int tid = threadIdx.x;
    for (int i = tid; i < SORT_W; i += 256) { hist[i] = 0; cur[i] = 0; }
    __syncthreads();
    const int base = blockIdx.x * (P1_EPT * 256);
#pragma unroll
    for (int k = 0; k < P1_EPT; ++k) {
        int e = base + k * 256 + tid;
        if (e < E) atomicAdd(&hist[ei[E + e] >> SORT_SH], 1);
    }
    __syncthreads();
    for (int i = tid; i < SORT_W; i += 256)
        if (hist[i]) goff[i] = atomicAdd(&bcur[i], hist[i]);
    __syncthreads();
#pragma unroll
    for (int k = 0; k < P1_EPT; ++k) {
        int e = base + k * 256 + tid;
        if (e < E) {
            int v = ei[E + e], u = ei[e];
            int b = v >> SORT_SH;
            int p = goff[b] + atomicAdd(&cur[b], 1);
            if (p < SORT_CAP) sorted[(size_t)b * SORT_CAP + p] = (int2){u, v};
        }
    }
}

// ---------------- shared gemm body: Y[n,CO](bf16) = A[n,128] @ W[128,CO] ----
// 16x16x32 layouts (m89-verified): A[m=lane&15][k=(lane>>4)*8+j],
// B[k][n=lane&15], C/D col=lane&15 row=(lane>>4)*4+i.
template <int CO, bool ABF>
__device__ __forceinline__ void gemm_body(char* smem, int row0,
        const void* __restrict__ Xv, const ushort* __restrict__ WT,
        ushort* __restrict__ Y, int n) {
    constexpr int LDW = 136;
    constexpr int NT = CO / 16;
    ushort* Ws = (ushort*)smem;
    const int tid = threadIdx.x, wave = tid >> 6, lane = tid & 63;
    const int m = lane & 15, q = lane >> 4;

#pragma unroll
    for (int c = 0; c < CO / 16; ++c) {
        int id = tid + c * 256;
        int r = id >> 4, h8 = id & 15;
        *(int4*)&Ws[r * LDW + h8 * 8] = ((const int4*)(WT + r * C_IN))[h8];
    }
    __syncthreads();

    const int rowA = min(row0 + wave * 16 + m, n - 1);
    floatx4 acc[NT];
#pragma unroll
    for (int c = 0; c < NT; ++c) acc[c] = (floatx4){0.f, 0.f, 0.f, 0.f};

#pragma unroll
    for (int s = 0; s < 4; ++s) {            // k = 32*s .. 32*s+31
        short8 af;
        if constexpr (ABF) {
            af = *(const short8*)((const ushort*)Xv + (size_t)rowA * C_IN + s * 32 + q * 8);
        } else {
            const float* xp = (const float*)Xv + (size_t)rowA * C_IN + s * 32 + q * 8;
            float4 a0 = *(const float4*)xp;
            float4 a1 = *(const float4*)(xp + 4);
            union { unsigned short us[8]; short8 v; } t;
            t.us[0] = f2bf(a0.x); t.us[1] = f2bf(a0.y); t.us[2] = f2bf(a0.z); t.us[3] = f2bf(a0.w);
            t.us[4] = f2bf(a1.x); t.us[5] = f2bf(a1.y); t.us[6] = f2bf(a1.z); t.us[7] = f2bf(a1.w);
            af = t.v;
        }
#pragma unroll
        for (int c = 0; c < NT; ++c) {
            short8 bf = *(short8*)&Ws[(c * 16 + m) * LDW + s * 32 + q * 8];
            acc[c] = __builtin_amdgcn_mfma_f32_16x16x32_bf16(af, bf, acc[c], 0, 0, 0);
        }
    }
#pragma unroll
    for (int c = 0; c < NT; ++c)
#pragma unroll
        for (int i = 0; i < 4; ++i) {
            int rr = row0 + wave * 16 + q * 4 + i;
            if (rr < n) Y[(size_t)rr * CO + c * 16 + m] = f2bf(acc[c][i]);
        }
}

// ---------------- Phase B (per-bucket CSR via LDS atomics) + fused gemm1 ----
// Emits slots with the self-loop appended (slots[v][deg]=v) and cnt = deg+1.
__global__ __launch_bounds__(256) void csr_gemm1_kernel(
        const int2* __restrict__ sorted, const int* __restrict__ bcur,
        int* __restrict__ cnt, float* __restrict__ dinv,
        int* __restrict__ slots,
        const float* __restrict__ X, const ushort* __restrict__ W1T,
        ushort* __restrict__ h1, int n) {
    __shared__ __align__(16) char smem[C_MID * 136 * 2];
    if (blockIdx.x < SORT_W) {
        int* lc = (int*)smem;                  // 512 local degree counters
        const int b = blockIdx.x, tid = threadIdx.x;
        const int base_v = b << SORT_SH;
        for (int i = tid; i < 512; i += 256) lc[i] = 0;
        __syncthreads();
        const int nb = min(bcur[b], SORT_CAP);
        const int2* src = sorted + (size_t)b * SORT_CAP;
        for (int i = tid; i < nb; i += 256) {
            int2 e = src[i];
            int pos = atomicAdd(&lc[e.y - base_v], 1);   // LDS atomic
            if (pos < SLOT_CAP - 1) slots[(size_t)e.y * SLOT_CAP + pos] = e.x;
        }
        __syncthreads();
        for (int i = tid; i < 512; i += 256) {
            int v = base_v + i;
            if (v < n) {
                int deg = lc[i];
                int st = min(deg, SLOT_CAP - 1);
                slots[(size_t)v * SLOT_CAP + st] = v;    // self-loop slot
                cnt[v] = st + 1;
                dinv[v] = rsqrtf((float)(deg + 1));
            }
        }
        return;
    }
    gemm_body<C_MID, false>(smem, (blockIdx.x - SORT_W) * 64, X, W1T, h1, n);
}

// ---------------- aggregation: 2 nodes/wave, straight-line 24-row window ---
// R9 core (best measured): register gathers + sched_barrier. OUT_MODE:
//   0 = f32 store (agg2, adds bias),
//   2 = fused gemm2: rows -> LDS -> per-wave 4x MFMA vs W2T -> bf16 h3
//       (bias deferred to agg2; identical math to old h2->gemm2 path).
template <int C, bool DO_RRELU, int OUT_MODE>
__global__ __launch_bounds__(256) void agg_kernel(const ushort* __restrict__ H,
                                                  const int* __restrict__ slots,
                                                  const int* __restrict__ cnt,
                                                  const float* __restrict__ dinv,
                                                  const float* __restrict__ bias,
                                                  void* __restrict__ outv, int n,
                                                  const ushort* __restrict__ W2T) {
    constexpr int GS = C / 8;        // 16 (C=128) / 8 (C=64)
    constexpr int NG = 64 / GS;      // rows per load: 4 / 8
    constexpr int NCH = 24 / NG;     // straight-line chunks per node: 6 / 3
    __shared__ ushort Hs[OUT_MODE == 2 ? 8 * 136 : 8];  // padded rows (bank-safe)
    __shared__ int    Vs[8];
    const int wave = threadIdx.x >> 6, lane = threadIdx.x & 63;
    int vA = blockIdx.x * 8 + wave * 2;
    if constexpr (OUT_MODE == 2) {
        vA = min(vA, n - 2);          // no early return: all waves reach syncthreads
    } else {
        if (vA >= n) return;
    }
    const int vB = (vA + 1 < n) ? vA + 1 : vA;   // odd tail: duplicate (benign)

    // prologue: all loads issued up front, minimal dependency chains
    int rawA = slots[(size_t)vA * SLOT_CAP + lane];
    int rawB = slots[(size_t)vB * SLOT_CAP + lane];
    const int limA = cnt[vA], limB = cnt[vB];
    const float dvA = dinv[vA], dvB = dinv[vB];
    const int uA = min(max(rawA, 0), n - 1);     // poison-safe
    const int uB = min(max(rawB, 0), n - 1);
    const float wA_l = dinv[uA] * dvA;
    const float wB_l = dinv[uB] * dvB;
    const int lastA = limA - 1, lastB = limB - 1;

    const int g = lane / GS, s = lane % GS;

    // issue all 2*NCH gathers concurrently
    float wwA[NCH], wwB[NCH];
    int4 ddA[NCH], ddB[NCH];
#pragma unroll
    for (int t = 0; t < NCH; ++t) {
        int jj = t * NG + g;
        int cA = jj < lastA ? jj : lastA;
        int cB = jj < lastB ? jj : lastB;
        int usA = __shfl(uA, cA), usB = __shfl(uB, cB);
        float wsA = __shfl(wA_l, cA), wsB = __shfl(wB_l, cB);
        wwA[t] = (jj < limA) ? wsA : 0.f;
        wwB[t] = (jj < limB) ? wsB : 0.f;
        ddA[t] = *(const int4*)(H + (size_t)usA * C + s * 8);
        ddB[t] = *(const int4*)(H + (size_t)usB * C + s * 8);
    }
    __builtin_amdgcn_sched_barrier(0);

    f32x2 accA[4], accB[4];
#pragma unroll
    for (int k = 0; k < 4; ++k) { accA[k] = (f32x2){0.f, 0.f}; accB[k] = (f32x2){0.f, 0.f}; }
#pragma unroll
    for (int t = 0; t < NCH; ++t) {
        accA[0] += bfpair(ddA[t].x) * wwA[t]; accA[1] += bfpair(ddA[t].y) * wwA[t];
        accA[2] += bfpair(ddA[t].z) * wwA[t]; accA[3] += bfpair(ddA[t].w) * wwA[t];
        accB[0] += bfpair(ddB[t].x) * wwB[t]; accB[1] += bfpair(ddB[t].y) * wwB[t];
        accB[2] += bfpair(ddB[t].z) * wwB[t]; accB[3] += bfpair(ddB[t].w) * wwB[t];
    }
    // rare tails (wave-uniform, P(lim>24) ~ 3.4% each)
    for (int j = 24; j < limA; j += NG) {
        int jj = j + g;
        int c = jj < lastA ? jj : lastA;
        int u = __shfl(uA, c);
        float wv = __shfl(wA_l, c);
        float wgt = (jj < limA) ? wv : 0.f;
        const int4 d = *(const int4*)(H + (size_t)u * C + s * 8);
        accA[0] += bfpair(d.x) * wgt; accA[1] += bfpair(d.y) * wgt;
        accA[2] += bfpair(d.z) * wgt; accA[3] += bfpair(d.w) * wgt;
    }
    for (int j = 24; j < limB; j += NG) {
        int jj = j + g;
        int c = jj < lastB ? jj : lastB;
        int u = __shfl(uB, c);
        float wv = __shfl(wB_l, c);
        float wgt = (jj < limB) ? wv : 0.f;
        const int4 d = *(const int4*)(H + (size_t)u * C + s * 8);
        accB[0] += bfpair(d.x) * wgt; accB[1] += bfpair(d.y) * wgt;
        accB[2] += bfpair(d.z) * wgt; accB[3] += bfpair(d.w) * wgt;
    }

    float a[8], b8[8];
#pragma unroll
    for (int k = 0; k < 4; ++k) {
        a[2 * k] = accA[k].x; a[2 * k + 1] = accA[k].y;
        b8[2 * k] = accB[k].x; b8[2 * k + 1] = accB[k].y;
    }
#pragma unroll
    for (int k = 0; k < 8; ++k)
#pragma unroll
        for (int off = GS; off < 64; off <<= 1) {
            a[k] += __shfl_xor(a[k], off);
            b8[k] += __shfl_xor(b8[k], off);
        }

    if constexpr (OUT_MODE == 2) {
        // ---- fused gemm2 epilogue ----
        if (g < 2) {
            const int v = (g == 0) ? vA : vB;
            union { ushort us[8]; int4 v4; } o;
#pragma unroll
            for (int k = 0; k < 8; ++k) {
                float t = (g == 0) ? a[k] : b8[k];
                t += bias[s * 8 + k];
                if (DO_RRELU) t = (t >= 0.f) ? t : t * kSlope;
                o.us[k] = f2bf(t);
            }
            *(int4*)&Hs[(wave * 2 + g) * 136 + s * 8] = o.v4;
            if (s == 0) Vs[wave * 2 + g] = v;
        }
        __syncthreads();
        // 16(rows; 8 valid)x128 @ 128x16 per wave; wave w covers cols w*16..w*16+15
        const int m2 = lane & 15, q2 = lane >> 4;
        floatx4 acc2 = (floatx4){0.f, 0.f, 0.f, 0.f};
#pragma unroll
        for (int s2 = 0; s2 < 4; ++s2) {
            short8 af = *(short8*)&Hs[m2 * 136 + s2 * 32 + q2 * 8];
            short8 bf = *(const short8*)(W2T + (size_t)(wave * 16 + m2) * C_MID + s2 * 32 + q2 * 8);
            acc2 = __builtin_amdgcn_mfma_f32_16x16x32_bf16(af, bf, acc2, 0, 0, 0);
        }
        ushort* Y2 = (ushort*)outv;
#pragma unroll
        for (int i = 0; i < 4; ++i) {
            int node = q2 * 4 + i;            // D row; rows 8..15 are garbage
            if (node < 8)
                Y2[(size_t)Vs[node] * C_OUT2 + wave * 16 + m2] = f2bf(acc2[i]);
        }
    } else if (g < 2) {
        const int v = (g == 0) ? vA : vB;
        float r[8];
#pragma unroll
        for (int k = 0; k < 8; ++k) {
            float t = (g == 0) ? a[k] : b8[k];
            r[k] = t + bias[s * 8 + k];
            if (DO_RRELU) r[k] = (r[k] >= 0.f) ? r[k] : r[k] * kSlope;
        }
        float* op = (float*)outv + (size_t)v * C + s * 8;
        *(float4*)op       = (float4){r[0], r[1], r[2], r[3]};
        *(float4*)(op + 4) = (float4){r[4], r[5], r[6], r[7]};
    }
}

extern "C" void kernel_launch(void* const* d_in, const int* in_sizes, int n_in,
                              void* d_out, int out_size, void* d_ws, size_t ws_size,
                              hipStream_t stream) {
    const float* x  = (const float*)d_in[0];
    const int*   ei = (const int*)d_in[1];
    const float* W1 = (const float*)d_in[2];
    const float* b1 = (const float*)d_in[3];
    const float* W2 = (const float*)d_in[4];
    const float* b2 = (const float*)d_in[5];
    const int n = in_sizes[0] / C_IN;   // 100000
    const int E = in_sizes[1] / 2;      // 1600000

    char* w = (char*)d_ws;
    auto alloc = [&](size_t bytes) -> char* {
        char* p = w; w += (bytes + 255) & ~(size_t)255; return p;
    };
    int*    cnt    = (int*)alloc((size_t)n * 4);
    float*  dinv   = (float*)alloc((size_t)n * 4);
    int*    slots  = (int*)alloc((size_t)n * SLOT_CAP * 4);
    ushort* h1     = (ushort*)alloc((size_t)n * C_MID * 2);   // bf16 (gemm1 out)
    ushort* h3     = (ushort*)alloc((size_t)n * C_OUT2 * 2);  // bf16 (fused gemm2 out)
    ushort* W1T    = (ushort*)alloc((size_t)C_MID * C_IN * 2);
    ushort* W2T    = (ushort*)alloc((size_t)C_OUT2 * C_MID * 2);
    int2*   sorted = (int2*)alloc((size_t)SORT_W * SORT_CAP * 8);
    int*    bcur   = (int*)alloc((size_t)SORT_W * 4);

    const int p1b = (E + P1_EPT * 256 - 1) / (P1_EPT * 256);   // 782
    const int prep_blocks = (C_MID * C_IN + C_OUT2 * C_MID + 255) / 256;  // 96
    const int gemm1_blocks = (n + 63) / 64;                    // 1563

    hipMemsetAsync(bcur, 0, (size_t)SORT_W * 4, stream);
    sort_prep_kernel<<<p1b + prep_blocks, 256, 0, stream>>>(
        ei, sorted, bcur, W1, W2, W1T, W2T, E, p1b);
    csr_gemm1_kernel<<<SORT_W + gemm1_blocks, 256, 0, stream>>>(
        sorted, bcur, cnt, dinv, slots, x, W1T, h1, n);
    agg_kernel<C_MID, true, 2><<<(n + 7) / 8, 256, 0, stream>>>(
        h1, slots, cnt, dinv, b1, h3, n, W2T);
    agg_kernel<C_OUT2, false, 0><<<(n + 7) / 8, 256, 0, stream>>>(
        h3, slots, cnt, dinv, b2, d_out, n, nullptr);
}